// Round 7
// baseline (373.325 us; speedup 1.0000x reference)
//
#include <hip/hip_runtime.h>

#define NN 512
#define CC 1024
#define OO 256
#define VV 68
#define PP 7
#define NC (NN*CC)
#define MM (PP*NN)        // 3584 GEMM rows, m = p*512 + n
#define NV_CNT 34816.0f   // N*T*V = 512*68

typedef float floatx4 __attribute__((ext_vector_type(4)));

__device__ __forceinline__ int part_of(int v){
  return (v>=17)+(v>=22)+(v>=27)+(v>=36)+(v>=42)+(v>=48);
}

// ---------------------------------------------------------------------------
// Decomposed pipeline (R7). Evidence: monolithic per-n kernel is grid-capped
// at 2 blocks/CU -> latency-bound at every phase (R2 93us best; R3-R6 worse).
// Each phase now gets its ideal grid; S/S2/h round-trips are L3-resident
// (14-28MB << 256MB L3).
// ---------------------------------------------------------------------------

// K1: streaming part-sum (VERBATIM from R1, verified passing). 4096 blocks x
// 128 rows. Coalesced f4 loads -> LDS transpose stg[v][row] (stride 129).
// 256 threads reduce half-rows (34 v each, wave-uniform specialization so
// s[]/q2[] stay statically indexed -> VGPRs), combine via LDS.
__global__ __launch_bounds__(256) void k1_partsum(const float* __restrict__ x,
    float* __restrict__ S, float* __restrict__ S2){
  __shared__ float stg[68*129];                  // 35088 B
  int R = blockIdx.x*128;                        // first row of block
  const float4* src = (const float4*)(x + (size_t)R*VV);
  #pragma unroll
  for (int k=0;k<9;k++){
    int g = k*256 + threadIdx.x;                 // f4 idx in [0,2176)
    if (k==8 && threadIdx.x>=128) break;
    float4 v4 = src[g];
    int row = g/17, q = g - row*17;
    stg[(q*4+0)*129 + row] = v4.x;
    stg[(q*4+1)*129 + row] = v4.y;
    stg[(q*4+2)*129 + row] = v4.z;
    stg[(q*4+3)*129 + row] = v4.w;
  }
  __syncthreads();

  int row  = threadIdx.x & 127;
  int half = threadIdx.x >> 7;                   // wave-uniform
  float s[PP], q2[PP];
  #pragma unroll
  for (int p=0;p<PP;p++){ s[p]=0.f; q2[p]=0.f; }
  if (half==0){
    #pragma unroll
    for (int v=0; v<34; v++){
      int p = part_of(v);                        // constant-folds
      float e = stg[v*129 + row];
      s[p] += e;
      q2[p] = fmaf(e, e, q2[p]);
    }
  } else {
    #pragma unroll
    for (int v=34; v<68; v++){
      int p = part_of(v);
      float e = stg[v*129 + row];
      s[p] += e;
      q2[p] = fmaf(e, e, q2[p]);
    }
  }
  __syncthreads();
  float* hs = stg;                               // reuse: 128*7
  float* hq = stg + 128*PP;
  if (half==1){
    #pragma unroll
    for (int p=0;p<PP;p++){ hs[row*PP+p]=s[p]; hq[row*PP+p]=q2[p]; }
  }
  __syncthreads();
  if (half==0){
    int r = R + row;
    #pragma unroll
    for (int p=0;p<PP;p++){
      S [p*NC + r] = s[p]  + hs[row*PP+p];
      S2[p*NC + r] = q2[p] + hq[row*PP+p];
    }
  }
}

// K2: GEMM h[m][o] = sum_c S[m][c] * w1[o][c]; m=(p,n) flat (S's natural
// layout: p*NC + n*1024 + c = m*1024 + c). M=3584, K=1024, N(o)=256.
// 32m x 32o tiles -> grid 896 (3.5 blocks/CU); LDS 17KB, VGPR small ->
// ~14 waves/CU. LDS tiles in [kk][m] / [kk][o] layout so the inner loop
// reads float2 (8B-aligned, pad 34 even) conflict-free with broadcast.
// Coalesced f4 global loads (16-f4 runs); 4-way LDS write conflicts on
// staging accepted (global coalescing >> LDS write cost).
__global__ __launch_bounds__(256) void k2_gemm(const float* __restrict__ S,
    const float* __restrict__ w1, float* __restrict__ h){
  __shared__ float As[64][34];                   // 8704 B
  __shared__ float Bs[64][34];                   // 8704 B
  int b  = blockIdx.x;                           // 896 = 112 * 8
  int bm = b & 127 ? b % 112 : b % 112;          // (kept simple below)
  bm = b % 112;
  int bo = b / 112;
  int m0 = bm*32, o0 = bo*32;
  int t  = threadIdx.x;
  int to = t & 15, tm = t >> 4;                  // lanes vary to -> coalesced h
  float acc00=0.f, acc01=0.f, acc10=0.f, acc11=0.f;

  const float4* S4 = (const float4*)S;
  const float4* W4 = (const float4*)w1;
  for (int cc=0; cc<1024; cc+=64){
    int ccg = cc >> 2;                           // f4 base
    #pragma unroll
    for (int it=0; it<2; ++it){                  // stage A: 32m x 16 f4
      int ml = it*16 + (t>>4);
      int kg = t & 15;
      float4 v = S4[(size_t)(m0+ml)*256 + ccg + kg];
      As[kg*4+0][ml] = v.x;
      As[kg*4+1][ml] = v.y;
      As[kg*4+2][ml] = v.z;
      As[kg*4+3][ml] = v.w;
    }
    #pragma unroll
    for (int it=0; it<2; ++it){                  // stage B: 32o x 16 f4
      int ol = it*16 + (t>>4);
      int kg = t & 15;
      float4 v = W4[(size_t)(o0+ol)*256 + ccg + kg];
      Bs[kg*4+0][ol] = v.x;
      Bs[kg*4+1][ol] = v.y;
      Bs[kg*4+2][ol] = v.z;
      Bs[kg*4+3][ol] = v.w;
    }
    __syncthreads();
    #pragma unroll
    for (int kk=0; kk<64; ++kk){
      float2 av = *(const float2*)&As[kk][tm*2];
      float2 bv = *(const float2*)&Bs[kk][to*2];
      acc00 = fmaf(av.x, bv.x, acc00);
      acc01 = fmaf(av.x, bv.y, acc01);
      acc10 = fmaf(av.y, bv.x, acc10);
      acc11 = fmaf(av.y, bv.y, acc11);
    }
    __syncthreads();
  }
  float2 r0; r0.x = acc00; r0.y = acc01;
  float2 r1; r1.x = acc10; r1.y = acc11;
  *(float2*)(h + (size_t)(m0 + tm*2    )*256 + o0 + to*2) = r0;
  *(float2*)(h + (size_t)(m0 + tm*2 + 1)*256 + o0 + to*2) = r1;
}

// K3s: per n (512 blocks x 256 thr): read h[(p*512+n)*256 + o], scale by
// inv_cnt, +b1, mean/max over o, softmax over p -> att. (Reduce code is
// R2's verified path.)
__global__ __launch_bounds__(256) void k3_soft(const float* __restrict__ h,
    const float* __restrict__ b1, const float* __restrict__ w2,
    const float* __restrict__ b2, float* __restrict__ att){
  int n = blockIdx.x;
  int t = threadIdx.x;
  __shared__ float red_s[4][PP], red_m[4][PP], pre[PP];
  const float inv_cnt[PP] = {1.f/17.f,1.f/5.f,1.f/5.f,1.f/9.f,1.f/6.f,1.f/6.f,1.f/20.f};
  float bo = b1[t];
  float hv[PP];
  #pragma unroll
  for (int p=0;p<PP;p++){
    float raw = h[(size_t)(p*NN + n)*256 + t];
    hv[p] = fmaf(raw, inv_cnt[p], bo);
  }
  int lane = t & 63, wid = t >> 6;
  #pragma unroll
  for (int p=0;p<PP;p++){
    float sm = hv[p], mx = hv[p];
    #pragma unroll
    for (int off=32; off>0; off>>=1){
      sm += __shfl_down(sm, off, 64);
      mx = fmaxf(mx, __shfl_down(mx, off, 64));
    }
    if (lane==0){ red_s[wid][p]=sm; red_m[wid][p]=mx; }
  }
  __syncthreads();
  if (t < PP){
    int p = t;
    float sm = red_s[0][p]+red_s[1][p]+red_s[2][p]+red_s[3][p];
    float mx = fmaxf(fmaxf(red_m[0][p],red_m[1][p]),
                     fmaxf(red_m[2][p],red_m[3][p]));
    pre[p] = w2[0]*(sm*(1.f/(float)OO)) + w2[1]*mx + b2[0];
  }
  __syncthreads();
  if (t == 0){
    float m = pre[0];
    #pragma unroll
    for (int p=1;p<PP;p++) m = fmaxf(m, pre[p]);
    float e[PP], sum=0.f;
    #pragma unroll
    for (int p=0;p<PP;p++){ e[p] = expf(pre[p]-m); sum += e[p]; }
    float inv = 1.f/sum;
    #pragma unroll
    for (int p=0;p<PP;p++) att[n*PP+p] = e[p]*inv;
  }
}

// K4p: BN partials. 2048 blocks x 256 thr; r = global (n,c) row. Reads
// S/S2 (L3-resident), att staged in LDS (n uniform per block).
__global__ __launch_bounds__(256) void k4_partial(const float* __restrict__ S,
    const float* __restrict__ S2, const float* __restrict__ att,
    float* __restrict__ partial){
  int r = blockIdx.x*256 + threadIdx.x;
  int n = r >> 10, c = r & 1023;
  __shared__ float sa[PP], sa2[PP];
  if (threadIdx.x < PP){
    float a = att[n*PP + threadIdx.x];
    sa[threadIdx.x] = a; sa2[threadIdx.x] = a*a;
  }
  __syncthreads();
  float sm=0.f, sq=0.f;
  #pragma unroll
  for (int p=0;p<PP;p++){
    sm = fmaf(sa[p],  S [(size_t)p*NC + r], sm);
    sq = fmaf(sa2[p], S2[(size_t)p*NC + r], sq);
  }
  partial[n*2048 + c]        = sm;
  partial[n*2048 + 1024 + c] = sq;
}

// K3b: single-dispatch reduce over n + BN finalize. 32 blocks x 256 thr.
__global__ __launch_bounds__(256) void k3b_finalize(const float* __restrict__ partial,
    const float* __restrict__ gamma, const float* __restrict__ beta,
    float* __restrict__ scsh){
  __shared__ float rs[8][32], rq[8][32];
  int cl = threadIdx.x & 31, grp = threadIdx.x >> 5;
  int c = blockIdx.x*32 + cl;
  float sm=0.f, sq=0.f;
  for (int i=0;i<64;i++){
    int n = grp*64 + i;
    sm += partial[n*2048 + c];
    sq += partial[n*2048 + 1024 + c];
  }
  rs[grp][cl] = sm; rq[grp][cl] = sq;
  __syncthreads();
  if (threadIdx.x < 32){
    float tsm=0.f, tsq=0.f;
    #pragma unroll
    for (int g=0; g<8; g++){ tsm += rs[g][threadIdx.x]; tsq += rq[g][threadIdx.x]; }
    int cc = blockIdx.x*32 + threadIdx.x;
    float mean = tsm * (1.0f/NV_CNT);
    float var  = tsq * (1.0f/NV_CNT) - mean*mean;
    float rstd = rsqrtf(var + 1e-5f);
    float sc = gamma[cc]*rstd;
    scsh[cc]        = sc;
    scsh[1024 + cc] = beta[cc] - mean*sc;
  }
}

// K4: out = relu( x*(att_j*sc + 1) + sh ); nontemporal stores.
__global__ __launch_bounds__(256) void k4_out(const float* __restrict__ x,
    const float* __restrict__ att, const float* __restrict__ scsh,
    float* __restrict__ out){
  int f = blockIdx.x*256 + threadIdx.x;          // float4 index, < NC*17
  int n = blockIdx.x / 68;                       // uniform within block
  __shared__ float s_att[PP];
  if (threadIdx.x < PP) s_att[threadIdx.x] = att[n*PP + threadIdx.x];
  __syncthreads();
  int r = f/17;
  int q = f - r*17;
  int v0 = q*4;
  int c = r & (CC-1);
  float4 xv = ((const float4*)x)[f];
  float sc = scsh[c];
  float sh = scsh[1024 + c];
  float vals[4];
  #pragma unroll
  for (int j=0;j<4;j++){
    int p = part_of(v0 + j);
    float a = s_att[p];
    float e = (j==0)?xv.x:(j==1)?xv.y:(j==2)?xv.z:xv.w;
    vals[j] = fmaxf(fmaf(e, fmaf(a, sc, 1.0f), sh), 0.0f);
  }
  floatx4 ov; ov.x=vals[0]; ov.y=vals[1]; ov.z=vals[2]; ov.w=vals[3];
  __builtin_nontemporal_store(ov, ((floatx4*)out) + f);
}

extern "C" void kernel_launch(void* const* d_in, const int* in_sizes, int n_in,
                              void* d_out, int out_size, void* d_ws, size_t ws_size,
                              hipStream_t stream) {
  const float* x     = (const float*)d_in[0];
  const float* w1    = (const float*)d_in[1];
  const float* b1    = (const float*)d_in[2];
  const float* w2    = (const float*)d_in[3];
  const float* b2    = (const float*)d_in[4];
  const float* gamma = (const float*)d_in[5];
  const float* beta  = (const float*)d_in[6];
  float* out = (float*)d_out;

  float* S       = (float*)d_ws;                 // 7*NC (14 MB)
  float* S2      = S + 7*NC;                     // 7*NC (14 MB)
  float* h       = S2 + 7*NC;                    // 3584*256 (3.5 MB)
  float* partial = h;                            // ALIAS: h dead after k3_soft;
                                                 // partial (4MB) >= h (3.5MB)
  float* scsh    = h + NN*2048;                  // 2048
  float* att     = scsh + 2048;                  // 512*7
  // ~33.6 MB of ws total (same budget as the R0 pipeline)

  k1_partsum  <<<NC/128,      256, 0, stream>>>(x, S, S2);
  k2_gemm     <<<(MM/32)*(OO/32), 256, 0, stream>>>(S, w1, h);
  k3_soft     <<<NN,          256, 0, stream>>>(h, b1, w2, b2, att);
  k4_partial  <<<NC/256,      256, 0, stream>>>(S, S2, att, partial);
  k3b_finalize<<<32,          256, 0, stream>>>(partial, gamma, beta, scsh);
  k4_out      <<<(NC*17)/256, 256, 0, stream>>>(x, att, scsh, out);
}